// Round 18
// baseline (1875.329 us; speedup 1.0000x reference)
//
#include <hip/hip_runtime.h>
#include <hip/hip_bf16.h>

typedef __bf16 bf16x8 __attribute__((ext_vector_type(8)));
typedef float  f32x4  __attribute__((ext_vector_type(4)));
typedef unsigned short us4 __attribute__((ext_vector_type(4)));
typedef unsigned short us8 __attribute__((ext_vector_type(8)));

#define N_CELLS 8000
#define N_GENES 8000
#define N_REG   20000
#define NF      100
#define KP      128
#define NFT     112
#define KSPLIT  25
#define NWIN    625

static __device__ __forceinline__ unsigned short f2bf_bits(float f) {
  unsigned u = __builtin_bit_cast(unsigned, f);
  u = (u + 0x7FFFu + ((u >> 16) & 1u)) >> 16;   // RNE
  return (unsigned short)u;
}
static __device__ __forceinline__ float bf2f(unsigned short s) {
  unsigned u = ((unsigned)s) << 16;
  return __builtin_bit_cast(float, u);
}
static __device__ __forceinline__ bf16x8 cvt8n(f32x4 v0, f32x4 v1) {
  bf16x8 r;
  r[0] = __builtin_bit_cast(__bf16, __float2bfloat16(v0[0]));
  r[1] = __builtin_bit_cast(__bf16, __float2bfloat16(v0[1]));
  r[2] = __builtin_bit_cast(__bf16, __float2bfloat16(v0[2]));
  r[3] = __builtin_bit_cast(__bf16, __float2bfloat16(v0[3]));
  r[4] = __builtin_bit_cast(__bf16, __float2bfloat16(v1[0]));
  r[5] = __builtin_bit_cast(__bf16, __float2bfloat16(v1[1]));
  r[6] = __builtin_bit_cast(__bf16, __float2bfloat16(v1[2]));
  r[7] = __builtin_bit_cast(__bf16, __float2bfloat16(v1[3]));
  return r;
}

// ---------------- pre-pass (verbatim round-13/15)
__global__ __launch_bounds__(256) void pre_kernel(
    const float* __restrict__ C1, const float* __restrict__ C2,
    const float* __restrict__ Cg, const float* __restrict__ Cr,
    const float* __restrict__ Ag, const float* __restrict__ Ar,
    unsigned short* __restrict__ T1, unsigned short* __restrict__ T2,
    unsigned short* __restrict__ Sg, unsigned short* __restrict__ Sr,
    float* __restrict__ accv) {
  __shared__ float srow[4][NF];
  int b = blockIdx.x, t = threadIdx.x;
  int w = t >> 6, lane = t & 63;
  if (b == 11000) {            // loss3
    float d = 0.f, na = 0.f, nr = 0.f;
    for (int i = t; i < NF * NF; i += 256) {
      float a = Ag[i], r = Ar[i];
      d = fmaf(a, r, d); na = fmaf(a, a, na); nr = fmaf(r, r, nr);
    }
    #pragma unroll
    for (int off = 32; off > 0; off >>= 1) {
      d += __shfl_xor(d, off); na += __shfl_xor(na, off); nr += __shfl_xor(nr, off);
    }
    __shared__ float r3[3][4];
    if (lane == 0) { r3[0][w] = d; r3[1][w] = na; r3[2][w] = nr; }
    __syncthreads();
    if (t == 0) {
      accv[2] = r3[0][0] + r3[0][1] + r3[0][2] + r3[0][3];
      accv[3] = r3[1][0] + r3[1][1] + r3[1][2] + r3[1][3];
      accv[4] = r3[2][0] + r3[2][1] + r3[2][2] + r3[2][3];
    }
    return;
  }
  const float* C; const float* W = nullptr;
  unsigned short* outR = nullptr; unsigned short* outT = nullptr;
  int i;
  if (b < 2000)      { C = C1; W = Ag; outT = T1; i = b * 4 + w; }
  else if (b < 4000) { C = C2; W = Ar; outT = T2; i = (b - 2000) * 4 + w; }
  else if (b < 6000) { C = Cg; outR = Sg; i = (b - 4000) * 4 + w; }
  else               { C = Cr; outR = Sr; i = (b - 6000) * 4 + w; }

  float v0 = C[i * NF + lane];
  float v1 = (lane < 36) ? C[i * NF + 64 + lane] : -3.0e38f;
  float m = fmaxf(v0, v1);
  #pragma unroll
  for (int off = 32; off > 0; off >>= 1) m = fmaxf(m, __shfl_xor(m, off));
  float e0 = __expf(v0 - m);
  float e1 = (lane < 36) ? __expf(v1 - m) : 0.f;
  float s = e0 + e1;
  #pragma unroll
  for (int off = 32; off > 0; off >>= 1) s += __shfl_xor(s, off);
  float inv = 1.f / s;
  e0 *= inv; e1 *= inv;

  if (outT == nullptr) {
    outR[i * KP + lane] = f2bf_bits(e0);
    outR[i * KP + 64 + lane] = (lane < 36) ? f2bf_bits(e1) : (unsigned short)0;
    return;
  }
  srow[w][lane] = e0;
  if (lane < 36) srow[w][64 + lane] = e1;
  __syncthreads();
  int c2 = 64 + lane;
  int c2c = (c2 < NF) ? c2 : NF - 1;
  float a0=0.f, a1=0.f, a2=0.f, a3=0.f;
  float d0=0.f, d1=0.f, d2=0.f, d3=0.f;
  #pragma unroll 4
  for (int k = 0; k < NF; k += 4) {
    float s0 = srow[w][k], s1 = srow[w][k+1], s2 = srow[w][k+2], s3 = srow[w][k+3];
    a0 = fmaf(s0, W[(k  )*NF + lane], a0);
    a1 = fmaf(s1, W[(k+1)*NF + lane], a1);
    a2 = fmaf(s2, W[(k+2)*NF + lane], a2);
    a3 = fmaf(s3, W[(k+3)*NF + lane], a3);
    d0 = fmaf(s0, W[(k  )*NF + c2c], d0);
    d1 = fmaf(s1, W[(k+1)*NF + c2c], d1);
    d2 = fmaf(s2, W[(k+2)*NF + c2c], d2);
    d3 = fmaf(s3, W[(k+3)*NF + c2c], d3);
  }
  outT[i * KP + lane] = f2bf_bits((a0 + a1) + (a2 + a3));
  outT[i * KP + c2]   = (c2 < NF) ? f2bf_bits((d0 + d1) + (d2 + d3)) : (unsigned short)0;
}

// ---------------- Bpack (verbatim round-13/15)
__global__ __launch_bounds__(256) void bpack_kernel(
    const unsigned short* __restrict__ Sr,
    unsigned short* __restrict__ Bpack) {
  __shared__ unsigned short lds[64 * 128];
  int t = threadIdx.x;
  long r0 = (long)blockIdx.x * 64;
  int w0 = blockIdx.x * 2;
  int nv = (int)((N_REG - r0 < 64) ? (N_REG - r0) : 64);
  #pragma unroll
  for (int q = 0; q < 4; ++q) {
    int idx = q * 256 + t;
    int row = idx >> 4, col8 = (idx & 15) * 8;
    us8 v = {0, 0, 0, 0, 0, 0, 0, 0};
    if (row < nv) v = *reinterpret_cast<const us8*>(Sr + (r0 + row) * KP + col8);
    *reinterpret_cast<us8*>(lds + row * 128 + col8) = v;
  }
  __syncthreads();
  for (int idx = t; idx < 896; idx += 256) {
    int win = idx / 448, rem = idx - win * 448;
    int ni = rem >> 6, lane = rem & 63;
    int lr = lane & 15, lg = lane >> 4;
    if (w0 + win < NWIN) {
      us8 v;
      #pragma unroll
      for (int e = 0; e < 8; ++e)
        v[e] = lds[(win * 32 + lg * 8 + e) * 128 + ni * 16 + lr];
      *reinterpret_cast<us8*>(Bpack + (((long)(w0 + win) * 7 + ni) << 9) + (lane << 3)) = v;
    }
  }
}

// ---------------- fused residual SSE (verbatim round-13/15)
__global__ __launch_bounds__(256, 3) void resid_kernel(
    const float* __restrict__ X,
    const unsigned short* __restrict__ Tm,
    const unsigned short* __restrict__ Sm,
    const float* __restrict__ bcol,
    const float* __restrict__ brow,
    int N, float* __restrict__ buckets) {
  __shared__ char ldsbuf[49152];
  char* ldsT = ldsbuf;
  char* ldsS = ldsbuf + 16384;
  int t = threadIdx.x;
  int wid = t >> 6, lane = t & 63;
  int lr = lane & 15, lg = lane >> 4;
  long r0blk = (long)blockIdx.y * 64;
  long c0blk = (long)blockIdx.x * 128;
  int r0 = (wid >> 1) * 32;
  int c0 = (wid & 1) * 64;

  bf16x8 sT[4], sS[8];
  #pragma unroll
  for (int i2 = 0; i2 < 4; ++i2) {
    int g = i2 * 256 + t, row = g >> 4, gi = g & 15;
    sT[i2] = *reinterpret_cast<const bf16x8*>(Tm + (r0blk + row) * KP + gi * 8);
  }
  #pragma unroll
  for (int i2 = 0; i2 < 8; ++i2) {
    int g = i2 * 256 + t, row = g >> 4, gi = g & 15;
    sS[i2] = *reinterpret_cast<const bf16x8*>(Sm + (c0blk + row) * KP + gi * 8);
  }

  f32x4 xv[2][4];
  #pragma unroll
  for (int ri = 0; ri < 2; ++ri) {
    long row = r0blk + r0 + ri * 16 + lr;
    #pragma unroll
    for (int ci = 0; ci < 4; ++ci) {
      long cb = c0blk + c0 + ci * 16 + lg * 4;
      if (cb < N) xv[ri][ci] = __builtin_nontemporal_load(
                    reinterpret_cast<const f32x4*>(X + row * N + cb));
      else        xv[ri][ci] = f32x4{0.f, 0.f, 0.f, 0.f};
    }
  }

  #pragma unroll
  for (int i2 = 0; i2 < 4; ++i2) {
    int g = i2 * 256 + t, row = g >> 4, gi = g & 15;
    int off = row * 256 + ((gi * 16) ^ ((row & 7) << 4));
    *reinterpret_cast<bf16x8*>(ldsT + off) = sT[i2];
  }
  #pragma unroll
  for (int i2 = 0; i2 < 8; ++i2) {
    int g = i2 * 256 + t, row = g >> 4, gi = g & 15;
    int off = row * 256 + ((gi * 16) ^ ((row & 7) << 4));
    *reinterpret_cast<bf16x8*>(ldsS + off) = sS[i2];
  }
  __syncthreads();

  f32x4 zero = {0.f, 0.f, 0.f, 0.f};
  f32x4 acc[4][2] = {{zero, zero}, {zero, zero}, {zero, zero}, {zero, zero}};
  #pragma unroll
  for (int ks = 0; ks < 4; ++ks) {
    bf16x8 a[4], bfr[2];
    #pragma unroll
    for (int ci = 0; ci < 4; ++ci) {
      int row = c0 + ci * 16 + lr;
      int off = row * 256 + (((ks * 64) + (lg * 16)) ^ ((row & 7) << 4));
      a[ci] = *reinterpret_cast<const bf16x8*>(ldsS + off);
    }
    #pragma unroll
    for (int ri = 0; ri < 2; ++ri) {
      int row = r0 + ri * 16 + lr;
      int off = row * 256 + (((ks * 64) + (lg * 16)) ^ ((row & 7) << 4));
      bfr[ri] = *reinterpret_cast<const bf16x8*>(ldsT + off);
    }
    #pragma unroll
    for (int ci = 0; ci < 4; ++ci)
      #pragma unroll
      for (int ri = 0; ri < 2; ++ri)
        acc[ci][ri] = __builtin_amdgcn_mfma_f32_16x16x32_bf16(a[ci], bfr[ri], acc[ci][ri], 0, 0, 0);
  }

  float brv[2];
  #pragma unroll
  for (int ri = 0; ri < 2; ++ri) brv[ri] = brow[r0blk + r0 + ri * 16 + lr];

  float sse = 0.f;
  #pragma unroll
  for (int ci = 0; ci < 4; ++ci) {
    long cb = c0blk + c0 + ci * 16 + lg * 4;
    if (cb < N) {
      f32x4 bc = *reinterpret_cast<const f32x4*>(bcol + cb);
      #pragma unroll
      for (int ri = 0; ri < 2; ++ri) {
        f32x4 x = xv[ri][ci];
        #pragma unroll
        for (int j = 0; j < 4; ++j) {
          float e = x[j] - acc[ci][ri][j] - bc[j] - brv[ri];
          sse = fmaf(e, e, sse);
        }
      }
    }
  }
  #pragma unroll
  for (int off = 32; off > 0; off >>= 1) sse += __shfl_xor(sse, off);
  __shared__ float wsum[4];
  if (lane == 0) wsum[wid] = sse;
  __syncthreads();
  if (t == 0)
    atomicAdd(&buckets[(blockIdx.y * gridDim.x + blockIdx.x) & 63],
              wsum[0] + wsum[1] + wsum[2] + wsum[3]);
}

// ---------------- ASr (round-15 ni-split depth-1; bf16 NT output)
__global__ __launch_bounds__(256, 4) void asr_kernel(
    const float* __restrict__ A,
    const unsigned short* __restrict__ Bpack,
    unsigned short* __restrict__ ASrN) {
  __shared__ char lds[2][16384];
  int t = threadIdx.x;
  int w = t >> 6, lane = t & 63;
  int lr = lane & 15, lg = lane >> 4;
  int gBase = blockIdx.x * 64;
  int kb0 = blockIdx.y * 800;
  int wk0 = blockIdx.y * 25;
  int ni0 = 2 * w;
  int ni1 = 2 * w + 1;
  bool has1 = (ni1 < 7);

  f32x4 zero = {0.f, 0.f, 0.f, 0.f};
  f32x4 acc[4][2];
  #pragma unroll
  for (int gt = 0; gt < 4; ++gt) { acc[gt][0] = zero; acc[gt][1] = zero; }
  f32x4 sreg[8];

  #pragma unroll
  for (int p = 0; p < 4; ++p) {
    int flat = p * 2048 + t * 8;
    int row = flat >> 7, kk = flat & 127;
    const float* src = A + (long)(gBase + row) * N_REG + kb0 + kk;
    sreg[2 * p]     = __builtin_nontemporal_load(reinterpret_cast<const f32x4*>(src));
    sreg[2 * p + 1] = __builtin_nontemporal_load(reinterpret_cast<const f32x4*>(src + 4));
  }

  #pragma unroll 1
  for (int it = 0; it < 7; ++it) {
    char* buf = lds[it & 1];
    if (it < 6) {
      #pragma unroll
      for (int p = 0; p < 4; ++p) {
        int flat = p * 2048 + t * 8;
        int row = flat >> 7, kk = flat & 127;
        int off = row * 256 + ((kk * 2) ^ ((row & 7) << 4));
        *reinterpret_cast<bf16x8*>(buf + off) = cvt8n(sreg[2 * p], sreg[2 * p + 1]);
      }
    } else {   // tail chunk: 32 k
      int row = t >> 2, kk = (t & 3) * 8;
      int off = row * 256 + ((kk * 2) ^ ((row & 7) << 4));
      *reinterpret_cast<bf16x8*>(buf + off) = cvt8n(sreg[0], sreg[1]);
    }
    __syncthreads();

    if (it < 5) {
      #pragma unroll
      for (int p = 0; p < 4; ++p) {
        int flat = p * 2048 + t * 8;
        int row = flat >> 7, kk = flat & 127;
        const float* src = A + (long)(gBase + row) * N_REG + kb0 + (it + 1) * 128 + kk;
        sreg[2 * p]     = __builtin_nontemporal_load(reinterpret_cast<const f32x4*>(src));
        sreg[2 * p + 1] = __builtin_nontemporal_load(reinterpret_cast<const f32x4*>(src + 4));
      }
    } else if (it == 5) {
      int row = t >> 2, kk = (t & 3) * 8;
      const float* src = A + (long)(gBase + row) * N_REG + kb0 + 768 + kk;
      sreg[0] = __builtin_nontemporal_load(reinterpret_cast<const f32x4*>(src));
      sreg[1] = __builtin_nontemporal_load(reinterpret_cast<const f32x4*>(src + 4));
    }

    int nk = (it < 6) ? 4 : 1;
    #pragma unroll 4
    for (int ks = 0; ks < nk; ++ks) {
      bf16x8 afr[4];
      #pragma unroll
      for (int gt = 0; gt < 4; ++gt) {
        int row = gt * 16 + lr;
        int off = row * 256 + (((ks * 64) + lg * 16) ^ ((row & 7) << 4));
        afr[gt] = *reinterpret_cast<const bf16x8*>(buf + off);
      }
      long wbase = ((long)(wk0 + it * 4 + ks) * 7) << 9;
      bf16x8 b0 = *reinterpret_cast<const bf16x8*>(
          Bpack + wbase + ((long)ni0 << 9) + (lane << 3));
      #pragma unroll
      for (int gt = 0; gt < 4; ++gt)
        acc[gt][0] = __builtin_amdgcn_mfma_f32_16x16x32_bf16(afr[gt], b0, acc[gt][0], 0, 0, 0);
      if (has1) {
        bf16x8 b1 = *reinterpret_cast<const bf16x8*>(
            Bpack + wbase + ((long)ni1 << 9) + (lane << 3));
        #pragma unroll
        for (int gt = 0; gt < 4; ++gt)
          acc[gt][1] = __builtin_amdgcn_mfma_f32_16x16x32_bf16(afr[gt], b1, acc[gt][1], 0, 0, 0);
      }
    }
  }

  unsigned short* slice = ASrN + (long)blockIdx.y * (N_GENES * NFT);
  #pragma unroll
  for (int gt = 0; gt < 4; ++gt) {
    int gb = gBase + gt * 16 + lg * 4;
    int f0 = ni0 * 16 + lr;
    #pragma unroll
    for (int j = 0; j < 4; ++j)
      __builtin_nontemporal_store(f2bf_bits(acc[gt][0][j]), &slice[(gb + j) * NFT + f0]);
    if (has1) {
      int f1 = ni1 * 16 + lr;
      #pragma unroll
      for (int j = 0; j < 4; ++j)
        __builtin_nontemporal_store(f2bf_bits(acc[gt][1][j]), &slice[(gb + j) * NFT + f1]);
    }
  }
}

// ---------------- loss4 pieces (bf16 slices; 400 blocks)
__global__ void l4red_kernel(const unsigned short* __restrict__ Sgbf,
                             const unsigned short* __restrict__ ASrN,
                             float* __restrict__ accv) {
  const int NV = N_GENES * NFT / 4;
  int t = blockIdx.x * blockDim.x + threadIdx.x;
  float d = 0.f, n1 = 0.f, n2 = 0.f;
  for (int q = t; q < NV; q += gridDim.x * blockDim.x) {
    int g = q / (NFT / 4);
    int f4 = (q - g * (NFT / 4)) * 4;
    float av0 = 0.f, av1 = 0.f, av2 = 0.f, av3 = 0.f;
    #pragma unroll
    for (int s = 0; s < KSPLIT; ++s) {
      us4 v = __builtin_nontemporal_load(
          reinterpret_cast<const us4*>(ASrN + (long)s * (N_GENES * NFT) + g * NFT + f4));
      av0 += bf2f(v[0]); av1 += bf2f(v[1]); av2 += bf2f(v[2]); av3 += bf2f(v[3]);
    }
    us4 sgb = *reinterpret_cast<const us4*>(Sgbf + g * KP + f4);
    float sg0 = bf2f(sgb[0]), sg1 = bf2f(sgb[1]), sg2 = bf2f(sgb[2]), sg3 = bf2f(sgb[3]);
    d = fmaf(sg0, av0, d); d = fmaf(sg1, av1, d); d = fmaf(sg2, av2, d); d = fmaf(sg3, av3, d);
    n1 = fmaf(sg0, sg0, n1); n1 = fmaf(sg1, sg1, n1); n1 = fmaf(sg2, sg2, n1); n1 = fmaf(sg3, sg3, n1);
    n2 = fmaf(av0, av0, n2); n2 = fmaf(av1, av1, n2); n2 = fmaf(av2, av2, n2); n2 = fmaf(av3, av3, n2);
  }
  #pragma unroll
  for (int off = 32; off > 0; off >>= 1) {
    d += __shfl_xor(d, off); n1 += __shfl_xor(n1, off); n2 += __shfl_xor(n2, off);
  }
  __shared__ float r3[3][4];
  int lane = threadIdx.x & 63, w = threadIdx.x >> 6;
  if (lane == 0) { r3[0][w] = d; r3[1][w] = n1; r3[2][w] = n2; }
  __syncthreads();
  if (threadIdx.x == 0) {
    atomicAdd(&accv[5], r3[0][0] + r3[0][1] + r3[0][2] + r3[0][3]);
    atomicAdd(&accv[6], r3[1][0] + r3[1][1] + r3[1][2] + r3[1][3]);
    atomicAdd(&accv[7], r3[2][0] + r3[2][1] + r3[2][2] + r3[2][3]);
  }
}

// ---------------- finalize (verbatim)
__global__ void fin_kernel(const float* __restrict__ accv,
                           const float* __restrict__ bk1,
                           const float* __restrict__ bk2,
                           const float* __restrict__ alpha,
                           float* __restrict__ out) {
  if (threadIdx.x == 0) {
    float s1 = 0.f, s2 = 0.f;
    for (int i = 0; i < 64; ++i) { s1 += bk1[i]; s2 += bk2[i]; }
    float loss1 = s1 / 64000000.0f;
    float loss2 = s2 / 160000000.0f;
    float loss3 = -accv[2] / (sqrtf(accv[3]) * sqrtf(accv[4]));
    float loss4 = -accv[5] / (sqrtf(accv[6]) * sqrtf(accv[7]));
    float l1 = alpha[0] * loss1, l2 = alpha[1] * loss2;
    float l3 = alpha[2] * loss3, l4 = alpha[3] * loss4;
    out[0] = l1 + l2 + l3 + l4;
    out[1] = l1; out[2] = l2; out[3] = l3; out[4] = l4;
  }
}

// ---------------- DIAG: pure-read HBM ceiling probe. 3 reps x (R+A)=3.84 GB.
// Results go to accv[14]/accv[15] (unused slots, memset each call) -> outputs
// unchanged, deterministic. NT=0: plain loads; NT=1: nontemporal loads.
template <int NT>
__global__ __launch_bounds__(256) void readdiag_kernel(
    const float* __restrict__ R, const float* __restrict__ A,
    float* __restrict__ accv) {
  long stride = (long)gridDim.x * 256 * 4;
  float s = 0.f;
  #pragma unroll 1
  for (int rep = 0; rep < 3; ++rep) {
    const float* r = R; const float* a = A;
    asm volatile("" : "+v"(r), "+v"(a));   // force re-read each rep
    for (long i = ((long)blockIdx.x * 256 + threadIdx.x) * 4; i < 160000000L; i += stride) {
      f32x4 v, w2;
      if (NT) {
        v  = __builtin_nontemporal_load(reinterpret_cast<const f32x4*>(r + i));
        w2 = __builtin_nontemporal_load(reinterpret_cast<const f32x4*>(a + i));
      } else {
        v  = *reinterpret_cast<const f32x4*>(r + i);
        w2 = *reinterpret_cast<const f32x4*>(a + i);
      }
      s += (v[0] + v[1]) + (v[2] + v[3]) + (w2[0] + w2[1]) + (w2[2] + w2[3]);
    }
  }
  #pragma unroll
  for (int off = 32; off > 0; off >>= 1) s += __shfl_xor(s, off);
  if ((threadIdx.x & 63) == 0) atomicAdd(&accv[14 + NT], s);
}

// ws layout (bytes): round-16 layout (bf16 ASrN)
//   0          : accv f32[16] | 64 bk1[64] | 320 bk2[64]
//   1024       : ASrN bf16 [25][8000][112]  (44,800,000)
//   44,801,024 : T1  bf16 [8000][128]
//   46,849,024 : T2  bf16 [8000][128]
//   48,897,024 : Sg  bf16 [8000][128]
//   50,945,024 : Sr  bf16 [20000][128]
//   56,065,024 : Bpack bf16 [625][7][64][8]

extern "C" void kernel_launch(void* const* d_in, const int* in_sizes, int n_in,
                              void* d_out, int out_size, void* d_ws, size_t ws_size,
                              hipStream_t stream) {
  const float* G  = (const float*)d_in[0];
  const float* R  = (const float*)d_in[1];
  const float* A  = (const float*)d_in[2];
  const float* C1 = (const float*)d_in[3];
  const float* C2 = (const float*)d_in[4];
  const float* Cg = (const float*)d_in[5];
  const float* Cr = (const float*)d_in[6];
  const float* Ag = (const float*)d_in[7];
  const float* Ar = (const float*)d_in[8];
  const float* bg = (const float*)d_in[9];
  const float* br = (const float*)d_in[10];
  const float* b1 = (const float*)d_in[11];
  const float* b2 = (const float*)d_in[12];
  const float* alpha = (const float*)d_in[13];

  char* ws = (char*)d_ws;
  float* accv           = (float*)(ws + 0);
  float* buckets1       = (float*)(ws + 64);
  float* buckets2       = (float*)(ws + 320);
  unsigned short* ASrN  = (unsigned short*)(ws + 1024);
  unsigned short* T1    = (unsigned short*)(ws + 44801024);
  unsigned short* T2    = (unsigned short*)(ws + 46849024);
  unsigned short* Sg    = (unsigned short*)(ws + 48897024);
  unsigned short* Sr    = (unsigned short*)(ws + 50945024);
  unsigned short* Bpack = (unsigned short*)(ws + 56065024);

  hipMemsetAsync(d_ws, 0, 576, stream);

  pre_kernel<<<11001, 256, 0, stream>>>(C1, C2, Cg, Cr, Ag, Ar,
                                        T1, T2, Sg, Sr, accv);
  bpack_kernel<<<313, 256, 0, stream>>>(Sr, Bpack);

  resid_kernel<<<dim3(63, 125), 256, 0, stream>>>(G, T1, Sg, bg, b1, N_GENES, buckets1);
  resid_kernel<<<dim3(157, 125), 256, 0, stream>>>(R, T2, Sr, br, b2, N_REG, buckets2);

  asr_kernel<<<dim3(125, KSPLIT), 256, 0, stream>>>(A, Bpack, ASrN);

  l4red_kernel<<<400, 256, 0, stream>>>(Sg, ASrN, accv);
  fin_kernel<<<1, 64, 0, stream>>>(accv, buckets1, buckets2, alpha, (float*)d_out);

  // DIAG: pure-read ceiling probes (output-preserving)
  readdiag_kernel<0><<<2048, 256, 0, stream>>>(R, A, accv);
  readdiag_kernel<1><<<2048, 256, 0, stream>>>(R, A, accv);
}

// Round 19
// 568.671 us; speedup vs baseline: 3.2977x; 3.2977x over previous
//
#include <hip/hip_runtime.h>
#include <hip/hip_bf16.h>

typedef __bf16 bf16x8 __attribute__((ext_vector_type(8)));
typedef float  f32x4  __attribute__((ext_vector_type(4)));
typedef unsigned short us4 __attribute__((ext_vector_type(4)));
typedef unsigned short us8 __attribute__((ext_vector_type(8)));

#define N_CELLS 8000
#define N_GENES 8000
#define N_REG   20000
#define NF      100
#define KP      128
#define NFT     112
#define KSPLIT  25
#define NWIN    625

static __device__ __forceinline__ unsigned short f2bf_bits(float f) {
  unsigned u = __builtin_bit_cast(unsigned, f);
  u = (u + 0x7FFFu + ((u >> 16) & 1u)) >> 16;   // RNE
  return (unsigned short)u;
}
static __device__ __forceinline__ float bf2f(unsigned short s) {
  unsigned u = ((unsigned)s) << 16;
  return __builtin_bit_cast(float, u);
}
static __device__ __forceinline__ bf16x8 cvt8n(f32x4 v0, f32x4 v1) {
  bf16x8 r;
  r[0] = __builtin_bit_cast(__bf16, __float2bfloat16(v0[0]));
  r[1] = __builtin_bit_cast(__bf16, __float2bfloat16(v0[1]));
  r[2] = __builtin_bit_cast(__bf16, __float2bfloat16(v0[2]));
  r[3] = __builtin_bit_cast(__bf16, __float2bfloat16(v0[3]));
  r[4] = __builtin_bit_cast(__bf16, __float2bfloat16(v1[0]));
  r[5] = __builtin_bit_cast(__bf16, __float2bfloat16(v1[1]));
  r[6] = __builtin_bit_cast(__bf16, __float2bfloat16(v1[2]));
  r[7] = __builtin_bit_cast(__bf16, __float2bfloat16(v1[3]));
  return r;
}

// ---------------- pre-pass (verbatim round-13/15)
__global__ __launch_bounds__(256) void pre_kernel(
    const float* __restrict__ C1, const float* __restrict__ C2,
    const float* __restrict__ Cg, const float* __restrict__ Cr,
    const float* __restrict__ Ag, const float* __restrict__ Ar,
    unsigned short* __restrict__ T1, unsigned short* __restrict__ T2,
    unsigned short* __restrict__ Sg, unsigned short* __restrict__ Sr,
    float* __restrict__ accv) {
  __shared__ float srow[4][NF];
  int b = blockIdx.x, t = threadIdx.x;
  int w = t >> 6, lane = t & 63;
  if (b == 11000) {            // loss3
    float d = 0.f, na = 0.f, nr = 0.f;
    for (int i = t; i < NF * NF; i += 256) {
      float a = Ag[i], r = Ar[i];
      d = fmaf(a, r, d); na = fmaf(a, a, na); nr = fmaf(r, r, nr);
    }
    #pragma unroll
    for (int off = 32; off > 0; off >>= 1) {
      d += __shfl_xor(d, off); na += __shfl_xor(na, off); nr += __shfl_xor(nr, off);
    }
    __shared__ float r3[3][4];
    if (lane == 0) { r3[0][w] = d; r3[1][w] = na; r3[2][w] = nr; }
    __syncthreads();
    if (t == 0) {
      accv[2] = r3[0][0] + r3[0][1] + r3[0][2] + r3[0][3];
      accv[3] = r3[1][0] + r3[1][1] + r3[1][2] + r3[1][3];
      accv[4] = r3[2][0] + r3[2][1] + r3[2][2] + r3[2][3];
    }
    return;
  }
  const float* C; const float* W = nullptr;
  unsigned short* outR = nullptr; unsigned short* outT = nullptr;
  int i;
  if (b < 2000)      { C = C1; W = Ag; outT = T1; i = b * 4 + w; }
  else if (b < 4000) { C = C2; W = Ar; outT = T2; i = (b - 2000) * 4 + w; }
  else if (b < 6000) { C = Cg; outR = Sg; i = (b - 4000) * 4 + w; }
  else               { C = Cr; outR = Sr; i = (b - 6000) * 4 + w; }

  float v0 = C[i * NF + lane];
  float v1 = (lane < 36) ? C[i * NF + 64 + lane] : -3.0e38f;
  float m = fmaxf(v0, v1);
  #pragma unroll
  for (int off = 32; off > 0; off >>= 1) m = fmaxf(m, __shfl_xor(m, off));
  float e0 = __expf(v0 - m);
  float e1 = (lane < 36) ? __expf(v1 - m) : 0.f;
  float s = e0 + e1;
  #pragma unroll
  for (int off = 32; off > 0; off >>= 1) s += __shfl_xor(s, off);
  float inv = 1.f / s;
  e0 *= inv; e1 *= inv;

  if (outT == nullptr) {
    outR[i * KP + lane] = f2bf_bits(e0);
    outR[i * KP + 64 + lane] = (lane < 36) ? f2bf_bits(e1) : (unsigned short)0;
    return;
  }
  srow[w][lane] = e0;
  if (lane < 36) srow[w][64 + lane] = e1;
  __syncthreads();
  int c2 = 64 + lane;
  int c2c = (c2 < NF) ? c2 : NF - 1;
  float a0=0.f, a1=0.f, a2=0.f, a3=0.f;
  float d0=0.f, d1=0.f, d2=0.f, d3=0.f;
  #pragma unroll 4
  for (int k = 0; k < NF; k += 4) {
    float s0 = srow[w][k], s1 = srow[w][k+1], s2 = srow[w][k+2], s3 = srow[w][k+3];
    a0 = fmaf(s0, W[(k  )*NF + lane], a0);
    a1 = fmaf(s1, W[(k+1)*NF + lane], a1);
    a2 = fmaf(s2, W[(k+2)*NF + lane], a2);
    a3 = fmaf(s3, W[(k+3)*NF + lane], a3);
    d0 = fmaf(s0, W[(k  )*NF + c2c], d0);
    d1 = fmaf(s1, W[(k+1)*NF + c2c], d1);
    d2 = fmaf(s2, W[(k+2)*NF + c2c], d2);
    d3 = fmaf(s3, W[(k+3)*NF + c2c], d3);
  }
  outT[i * KP + lane] = f2bf_bits((a0 + a1) + (a2 + a3));
  outT[i * KP + c2]   = (c2 < NF) ? f2bf_bits((d0 + d1) + (d2 + d3)) : (unsigned short)0;
}

// ---------------- Bpack (verbatim round-13/15)
__global__ __launch_bounds__(256) void bpack_kernel(
    const unsigned short* __restrict__ Sr,
    unsigned short* __restrict__ Bpack) {
  __shared__ unsigned short lds[64 * 128];
  int t = threadIdx.x;
  long r0 = (long)blockIdx.x * 64;
  int w0 = blockIdx.x * 2;
  int nv = (int)((N_REG - r0 < 64) ? (N_REG - r0) : 64);
  #pragma unroll
  for (int q = 0; q < 4; ++q) {
    int idx = q * 256 + t;
    int row = idx >> 4, col8 = (idx & 15) * 8;
    us8 v = {0, 0, 0, 0, 0, 0, 0, 0};
    if (row < nv) v = *reinterpret_cast<const us8*>(Sr + (r0 + row) * KP + col8);
    *reinterpret_cast<us8*>(lds + row * 128 + col8) = v;
  }
  __syncthreads();
  for (int idx = t; idx < 896; idx += 256) {
    int win = idx / 448, rem = idx - win * 448;
    int ni = rem >> 6, lane = rem & 63;
    int lr = lane & 15, lg = lane >> 4;
    if (w0 + win < NWIN) {
      us8 v;
      #pragma unroll
      for (int e = 0; e < 8; ++e)
        v[e] = lds[(win * 32 + lg * 8 + e) * 128 + ni * 16 + lr];
      *reinterpret_cast<us8*>(Bpack + (((long)(w0 + win) * 7 + ni) << 9) + (lane << 3)) = v;
    }
  }
}

// ---------------- fused residual SSE — 64x64 tiles, 32KB LDS, 5 blocks/CU.
// Wave layout: 4 waves as 2(row)x2(col); wave tile 32r x 32c; acc[2][2].
// wsum aliased into ldsbuf (extra barrier before reuse). Fragment/epilogue
// mapping identical to the verified 64x128 version (ci range 4->2).
__global__ __launch_bounds__(256, 5) void resid_kernel(
    const float* __restrict__ X,
    const unsigned short* __restrict__ Tm,
    const unsigned short* __restrict__ Sm,
    const float* __restrict__ bcol,
    const float* __restrict__ brow,
    int N, float* __restrict__ buckets) {
  __shared__ char ldsbuf[32768];
  char* ldsT = ldsbuf;            // [64][256B swizzled]
  char* ldsS = ldsbuf + 16384;    // [64][256B swizzled]
  float* wsum = (float*)ldsbuf;   // aliased; used only after end barrier
  int t = threadIdx.x;
  int wid = t >> 6, lane = t & 63;
  int lr = lane & 15, lg = lane >> 4;
  long r0blk = (long)blockIdx.y * 64;
  long c0blk = (long)blockIdx.x * 64;
  int r0 = (wid >> 1) * 32;
  int c0 = (wid & 1) * 32;

  bf16x8 sT[4], sS[4];
  #pragma unroll
  for (int i2 = 0; i2 < 4; ++i2) {
    int g = i2 * 256 + t, row = g >> 4, gi = g & 15;
    sT[i2] = *reinterpret_cast<const bf16x8*>(Tm + (r0blk + row) * KP + gi * 8);
  }
  #pragma unroll
  for (int i2 = 0; i2 < 4; ++i2) {
    int g = i2 * 256 + t, row = g >> 4, gi = g & 15;
    sS[i2] = *reinterpret_cast<const bf16x8*>(Sm + (c0blk + row) * KP + gi * 8);
  }

  f32x4 xv[2][2];
  #pragma unroll
  for (int ri = 0; ri < 2; ++ri) {
    long row = r0blk + r0 + ri * 16 + lr;
    #pragma unroll
    for (int ci = 0; ci < 2; ++ci) {
      long cb = c0blk + c0 + ci * 16 + lg * 4;
      if (cb < N) xv[ri][ci] = __builtin_nontemporal_load(
                    reinterpret_cast<const f32x4*>(X + row * N + cb));
      else        xv[ri][ci] = f32x4{0.f, 0.f, 0.f, 0.f};
    }
  }

  #pragma unroll
  for (int i2 = 0; i2 < 4; ++i2) {
    int g = i2 * 256 + t, row = g >> 4, gi = g & 15;
    int off = row * 256 + ((gi * 16) ^ ((row & 7) << 4));
    *reinterpret_cast<bf16x8*>(ldsT + off) = sT[i2];
  }
  #pragma unroll
  for (int i2 = 0; i2 < 4; ++i2) {
    int g = i2 * 256 + t, row = g >> 4, gi = g & 15;
    int off = row * 256 + ((gi * 16) ^ ((row & 7) << 4));
    *reinterpret_cast<bf16x8*>(ldsS + off) = sS[i2];
  }
  __syncthreads();

  f32x4 zero = {0.f, 0.f, 0.f, 0.f};
  f32x4 acc[2][2] = {{zero, zero}, {zero, zero}};
  #pragma unroll
  for (int ks = 0; ks < 4; ++ks) {
    bf16x8 a[2], bfr[2];
    #pragma unroll
    for (int ci = 0; ci < 2; ++ci) {
      int row = c0 + ci * 16 + lr;
      int off = row * 256 + (((ks * 64) + (lg * 16)) ^ ((row & 7) << 4));
      a[ci] = *reinterpret_cast<const bf16x8*>(ldsS + off);
    }
    #pragma unroll
    for (int ri = 0; ri < 2; ++ri) {
      int row = r0 + ri * 16 + lr;
      int off = row * 256 + (((ks * 64) + (lg * 16)) ^ ((row & 7) << 4));
      bfr[ri] = *reinterpret_cast<const bf16x8*>(ldsT + off);
    }
    #pragma unroll
    for (int ci = 0; ci < 2; ++ci)
      #pragma unroll
      for (int ri = 0; ri < 2; ++ri)
        acc[ci][ri] = __builtin_amdgcn_mfma_f32_16x16x32_bf16(a[ci], bfr[ri], acc[ci][ri], 0, 0, 0);
  }

  float brv[2];
  #pragma unroll
  for (int ri = 0; ri < 2; ++ri) brv[ri] = brow[r0blk + r0 + ri * 16 + lr];

  float sse = 0.f;
  #pragma unroll
  for (int ci = 0; ci < 2; ++ci) {
    long cb = c0blk + c0 + ci * 16 + lg * 4;
    if (cb < N) {
      f32x4 bc = *reinterpret_cast<const f32x4*>(bcol + cb);
      #pragma unroll
      for (int ri = 0; ri < 2; ++ri) {
        f32x4 x = xv[ri][ci];
        #pragma unroll
        for (int j = 0; j < 4; ++j) {
          float e = x[j] - acc[ci][ri][j] - bc[j] - brv[ri];
          sse = fmaf(e, e, sse);
        }
      }
    }
  }
  #pragma unroll
  for (int off = 32; off > 0; off >>= 1) sse += __shfl_xor(sse, off);
  __syncthreads();   // all panel ds_reads done before wsum aliases ldsbuf
  if (lane == 0) wsum[wid] = sse;
  __syncthreads();
  if (t == 0)
    atomicAdd(&buckets[(blockIdx.y * gridDim.x + blockIdx.x) & 63],
              wsum[0] + wsum[1] + wsum[2] + wsum[3]);
}

// ---------------- ASr (round-15 ni-split depth-1; bf16 NT output; verbatim)
__global__ __launch_bounds__(256, 4) void asr_kernel(
    const float* __restrict__ A,
    const unsigned short* __restrict__ Bpack,
    unsigned short* __restrict__ ASrN) {
  __shared__ char lds[2][16384];
  int t = threadIdx.x;
  int w = t >> 6, lane = t & 63;
  int lr = lane & 15, lg = lane >> 4;
  int gBase = blockIdx.x * 64;
  int kb0 = blockIdx.y * 800;
  int wk0 = blockIdx.y * 25;
  int ni0 = 2 * w;
  int ni1 = 2 * w + 1;
  bool has1 = (ni1 < 7);

  f32x4 zero = {0.f, 0.f, 0.f, 0.f};
  f32x4 acc[4][2];
  #pragma unroll
  for (int gt = 0; gt < 4; ++gt) { acc[gt][0] = zero; acc[gt][1] = zero; }
  f32x4 sreg[8];

  #pragma unroll
  for (int p = 0; p < 4; ++p) {
    int flat = p * 2048 + t * 8;
    int row = flat >> 7, kk = flat & 127;
    const float* src = A + (long)(gBase + row) * N_REG + kb0 + kk;
    sreg[2 * p]     = __builtin_nontemporal_load(reinterpret_cast<const f32x4*>(src));
    sreg[2 * p + 1] = __builtin_nontemporal_load(reinterpret_cast<const f32x4*>(src + 4));
  }

  #pragma unroll 1
  for (int it = 0; it < 7; ++it) {
    char* buf = lds[it & 1];
    if (it < 6) {
      #pragma unroll
      for (int p = 0; p < 4; ++p) {
        int flat = p * 2048 + t * 8;
        int row = flat >> 7, kk = flat & 127;
        int off = row * 256 + ((kk * 2) ^ ((row & 7) << 4));
        *reinterpret_cast<bf16x8*>(buf + off) = cvt8n(sreg[2 * p], sreg[2 * p + 1]);
      }
    } else {   // tail chunk: 32 k
      int row = t >> 2, kk = (t & 3) * 8;
      int off = row * 256 + ((kk * 2) ^ ((row & 7) << 4));
      *reinterpret_cast<bf16x8*>(buf + off) = cvt8n(sreg[0], sreg[1]);
    }
    __syncthreads();

    if (it < 5) {
      #pragma unroll
      for (int p = 0; p < 4; ++p) {
        int flat = p * 2048 + t * 8;
        int row = flat >> 7, kk = flat & 127;
        const float* src = A + (long)(gBase + row) * N_REG + kb0 + (it + 1) * 128 + kk;
        sreg[2 * p]     = __builtin_nontemporal_load(reinterpret_cast<const f32x4*>(src));
        sreg[2 * p + 1] = __builtin_nontemporal_load(reinterpret_cast<const f32x4*>(src + 4));
      }
    } else if (it == 5) {
      int row = t >> 2, kk = (t & 3) * 8;
      const float* src = A + (long)(gBase + row) * N_REG + kb0 + 768 + kk;
      sreg[0] = __builtin_nontemporal_load(reinterpret_cast<const f32x4*>(src));
      sreg[1] = __builtin_nontemporal_load(reinterpret_cast<const f32x4*>(src + 4));
    }

    int nk = (it < 6) ? 4 : 1;
    #pragma unroll 4
    for (int ks = 0; ks < nk; ++ks) {
      bf16x8 afr[4];
      #pragma unroll
      for (int gt = 0; gt < 4; ++gt) {
        int row = gt * 16 + lr;
        int off = row * 256 + (((ks * 64) + lg * 16) ^ ((row & 7) << 4));
        afr[gt] = *reinterpret_cast<const bf16x8*>(buf + off);
      }
      long wbase = ((long)(wk0 + it * 4 + ks) * 7) << 9;
      bf16x8 b0 = *reinterpret_cast<const bf16x8*>(
          Bpack + wbase + ((long)ni0 << 9) + (lane << 3));
      #pragma unroll
      for (int gt = 0; gt < 4; ++gt)
        acc[gt][0] = __builtin_amdgcn_mfma_f32_16x16x32_bf16(afr[gt], b0, acc[gt][0], 0, 0, 0);
      if (has1) {
        bf16x8 b1 = *reinterpret_cast<const bf16x8*>(
            Bpack + wbase + ((long)ni1 << 9) + (lane << 3));
        #pragma unroll
        for (int gt = 0; gt < 4; ++gt)
          acc[gt][1] = __builtin_amdgcn_mfma_f32_16x16x32_bf16(afr[gt], b1, acc[gt][1], 0, 0, 0);
      }
    }
  }

  unsigned short* slice = ASrN + (long)blockIdx.y * (N_GENES * NFT);
  #pragma unroll
  for (int gt = 0; gt < 4; ++gt) {
    int gb = gBase + gt * 16 + lg * 4;
    int f0 = ni0 * 16 + lr;
    #pragma unroll
    for (int j = 0; j < 4; ++j)
      __builtin_nontemporal_store(f2bf_bits(acc[gt][0][j]), &slice[(gb + j) * NFT + f0]);
    if (has1) {
      int f1 = ni1 * 16 + lr;
      #pragma unroll
      for (int j = 0; j < 4; ++j)
        __builtin_nontemporal_store(f2bf_bits(acc[gt][1][j]), &slice[(gb + j) * NFT + f1]);
    }
  }
}

// ---------------- loss4 pieces (bf16 slices; verbatim round-16)
__global__ void l4red_kernel(const unsigned short* __restrict__ Sgbf,
                             const unsigned short* __restrict__ ASrN,
                             float* __restrict__ accv) {
  const int NV = N_GENES * NFT / 4;
  int t = blockIdx.x * blockDim.x + threadIdx.x;
  float d = 0.f, n1 = 0.f, n2 = 0.f;
  for (int q = t; q < NV; q += gridDim.x * blockDim.x) {
    int g = q / (NFT / 4);
    int f4 = (q - g * (NFT / 4)) * 4;
    float av0 = 0.f, av1 = 0.f, av2 = 0.f, av3 = 0.f;
    #pragma unroll
    for (int s = 0; s < KSPLIT; ++s) {
      us4 v = __builtin_nontemporal_load(
          reinterpret_cast<const us4*>(ASrN + (long)s * (N_GENES * NFT) + g * NFT + f4));
      av0 += bf2f(v[0]); av1 += bf2f(v[1]); av2 += bf2f(v[2]); av3 += bf2f(v[3]);
    }
    us4 sgb = *reinterpret_cast<const us4*>(Sgbf + g * KP + f4);
    float sg0 = bf2f(sgb[0]), sg1 = bf2f(sgb[1]), sg2 = bf2f(sgb[2]), sg3 = bf2f(sgb[3]);
    d = fmaf(sg0, av0, d); d = fmaf(sg1, av1, d); d = fmaf(sg2, av2, d); d = fmaf(sg3, av3, d);
    n1 = fmaf(sg0, sg0, n1); n1 = fmaf(sg1, sg1, n1); n1 = fmaf(sg2, sg2, n1); n1 = fmaf(sg3, sg3, n1);
    n2 = fmaf(av0, av0, n2); n2 = fmaf(av1, av1, n2); n2 = fmaf(av2, av2, n2); n2 = fmaf(av3, av3, n2);
  }
  #pragma unroll
  for (int off = 32; off > 0; off >>= 1) {
    d += __shfl_xor(d, off); n1 += __shfl_xor(n1, off); n2 += __shfl_xor(n2, off);
  }
  __shared__ float r3[3][4];
  int lane = threadIdx.x & 63, w = threadIdx.x >> 6;
  if (lane == 0) { r3[0][w] = d; r3[1][w] = n1; r3[2][w] = n2; }
  __syncthreads();
  if (threadIdx.x == 0) {
    atomicAdd(&accv[5], r3[0][0] + r3[0][1] + r3[0][2] + r3[0][3]);
    atomicAdd(&accv[6], r3[1][0] + r3[1][1] + r3[1][2] + r3[1][3]);
    atomicAdd(&accv[7], r3[2][0] + r3[2][1] + r3[2][2] + r3[2][3]);
  }
}

// ---------------- finalize (verbatim)
__global__ void fin_kernel(const float* __restrict__ accv,
                           const float* __restrict__ bk1,
                           const float* __restrict__ bk2,
                           const float* __restrict__ alpha,
                           float* __restrict__ out) {
  if (threadIdx.x == 0) {
    float s1 = 0.f, s2 = 0.f;
    for (int i = 0; i < 64; ++i) { s1 += bk1[i]; s2 += bk2[i]; }
    float loss1 = s1 / 64000000.0f;
    float loss2 = s2 / 160000000.0f;
    float loss3 = -accv[2] / (sqrtf(accv[3]) * sqrtf(accv[4]));
    float loss4 = -accv[5] / (sqrtf(accv[6]) * sqrtf(accv[7]));
    float l1 = alpha[0] * loss1, l2 = alpha[1] * loss2;
    float l3 = alpha[2] * loss3, l4 = alpha[3] * loss4;
    out[0] = l1 + l2 + l3 + l4;
    out[1] = l1; out[2] = l2; out[3] = l3; out[4] = l4;
  }
}

// ws layout (bytes): round-16/18 layout (bf16 ASrN)
//   0          : accv f32[16] | 64 bk1[64] | 320 bk2[64]
//   1024       : ASrN bf16 [25][8000][112]  (44,800,000)
//   44,801,024 : T1  bf16 [8000][128]
//   46,849,024 : T2  bf16 [8000][128]
//   48,897,024 : Sg  bf16 [8000][128]
//   50,945,024 : Sr  bf16 [20000][128]
//   56,065,024 : Bpack bf16 [625][7][64][8]

extern "C" void kernel_launch(void* const* d_in, const int* in_sizes, int n_in,
                              void* d_out, int out_size, void* d_ws, size_t ws_size,
                              hipStream_t stream) {
  const float* G  = (const float*)d_in[0];
  const float* R  = (const float*)d_in[1];
  const float* A  = (const float*)d_in[2];
  const float* C1 = (const float*)d_in[3];
  const float* C2 = (const float*)d_in[4];
  const float* Cg = (const float*)d_in[5];
  const float* Cr = (const float*)d_in[6];
  const float* Ag = (const float*)d_in[7];
  const float* Ar = (const float*)d_in[8];
  const float* bg = (const float*)d_in[9];
  const float* br = (const float*)d_in[10];
  const float* b1 = (const float*)d_in[11];
  const float* b2 = (const float*)d_in[12];
  const float* alpha = (const float*)d_in[13];

  char* ws = (char*)d_ws;
  float* accv           = (float*)(ws + 0);
  float* buckets1       = (float*)(ws + 64);
  float* buckets2       = (float*)(ws + 320);
  unsigned short* ASrN  = (unsigned short*)(ws + 1024);
  unsigned short* T1    = (unsigned short*)(ws + 44801024);
  unsigned short* T2    = (unsigned short*)(ws + 46849024);
  unsigned short* Sg    = (unsigned short*)(ws + 48897024);
  unsigned short* Sr    = (unsigned short*)(ws + 50945024);
  unsigned short* Bpack = (unsigned short*)(ws + 56065024);

  hipMemsetAsync(d_ws, 0, 576, stream);

  pre_kernel<<<11001, 256, 0, stream>>>(C1, C2, Cg, Cr, Ag, Ar,
                                        T1, T2, Sg, Sr, accv);
  bpack_kernel<<<313, 256, 0, stream>>>(Sr, Bpack);

  resid_kernel<<<dim3(125, 125), 256, 0, stream>>>(G, T1, Sg, bg, b1, N_GENES, buckets1);
  resid_kernel<<<dim3(313, 125), 256, 0, stream>>>(R, T2, Sr, br, b2, N_REG, buckets2);

  asr_kernel<<<dim3(125, KSPLIT), 256, 0, stream>>>(A, Bpack, ASrN);

  l4red_kernel<<<400, 256, 0, stream>>>(Sg, ASrN, accv);
  fin_kernel<<<1, 64, 0, stream>>>(accv, buckets1, buckets2, alpha, (float*)d_out);
}

// Round 20
// 546.251 us; speedup vs baseline: 3.4331x; 1.0410x over previous
//
#include <hip/hip_runtime.h>
#include <hip/hip_bf16.h>

typedef __bf16 bf16x8 __attribute__((ext_vector_type(8)));
typedef float  f32x4  __attribute__((ext_vector_type(4)));
typedef unsigned short us4 __attribute__((ext_vector_type(4)));
typedef unsigned short us8 __attribute__((ext_vector_type(8)));

#define N_CELLS 8000
#define N_GENES 8000
#define N_REG   20000
#define NF      100
#define KP      128
#define NFT     112
#define KSPLIT  25
#define NWIN    625

static __device__ __forceinline__ unsigned short f2bf_bits(float f) {
  unsigned u = __builtin_bit_cast(unsigned, f);
  u = (u + 0x7FFFu + ((u >> 16) & 1u)) >> 16;   // RNE
  return (unsigned short)u;
}
static __device__ __forceinline__ float bf2f(unsigned short s) {
  unsigned u = ((unsigned)s) << 16;
  return __builtin_bit_cast(float, u);
}
static __device__ __forceinline__ bf16x8 cvt8n(f32x4 v0, f32x4 v1) {
  bf16x8 r;
  r[0] = __builtin_bit_cast(__bf16, __float2bfloat16(v0[0]));
  r[1] = __builtin_bit_cast(__bf16, __float2bfloat16(v0[1]));
  r[2] = __builtin_bit_cast(__bf16, __float2bfloat16(v0[2]));
  r[3] = __builtin_bit_cast(__bf16, __float2bfloat16(v0[3]));
  r[4] = __builtin_bit_cast(__bf16, __float2bfloat16(v1[0]));
  r[5] = __builtin_bit_cast(__bf16, __float2bfloat16(v1[1]));
  r[6] = __builtin_bit_cast(__bf16, __float2bfloat16(v1[2]));
  r[7] = __builtin_bit_cast(__bf16, __float2bfloat16(v1[3]));
  return r;
}

// ---------------- pre-pass (verbatim round-13/15)
__global__ __launch_bounds__(256) void pre_kernel(
    const float* __restrict__ C1, const float* __restrict__ C2,
    const float* __restrict__ Cg, const float* __restrict__ Cr,
    const float* __restrict__ Ag, const float* __restrict__ Ar,
    unsigned short* __restrict__ T1, unsigned short* __restrict__ T2,
    unsigned short* __restrict__ Sg, unsigned short* __restrict__ Sr,
    float* __restrict__ accv) {
  __shared__ float srow[4][NF];
  int b = blockIdx.x, t = threadIdx.x;
  int w = t >> 6, lane = t & 63;
  if (b == 11000) {            // loss3
    float d = 0.f, na = 0.f, nr = 0.f;
    for (int i = t; i < NF * NF; i += 256) {
      float a = Ag[i], r = Ar[i];
      d = fmaf(a, r, d); na = fmaf(a, a, na); nr = fmaf(r, r, nr);
    }
    #pragma unroll
    for (int off = 32; off > 0; off >>= 1) {
      d += __shfl_xor(d, off); na += __shfl_xor(na, off); nr += __shfl_xor(nr, off);
    }
    __shared__ float r3[3][4];
    if (lane == 0) { r3[0][w] = d; r3[1][w] = na; r3[2][w] = nr; }
    __syncthreads();
    if (t == 0) {
      accv[2] = r3[0][0] + r3[0][1] + r3[0][2] + r3[0][3];
      accv[3] = r3[1][0] + r3[1][1] + r3[1][2] + r3[1][3];
      accv[4] = r3[2][0] + r3[2][1] + r3[2][2] + r3[2][3];
    }
    return;
  }
  const float* C; const float* W = nullptr;
  unsigned short* outR = nullptr; unsigned short* outT = nullptr;
  int i;
  if (b < 2000)      { C = C1; W = Ag; outT = T1; i = b * 4 + w; }
  else if (b < 4000) { C = C2; W = Ar; outT = T2; i = (b - 2000) * 4 + w; }
  else if (b < 6000) { C = Cg; outR = Sg; i = (b - 4000) * 4 + w; }
  else               { C = Cr; outR = Sr; i = (b - 6000) * 4 + w; }

  float v0 = C[i * NF + lane];
  float v1 = (lane < 36) ? C[i * NF + 64 + lane] : -3.0e38f;
  float m = fmaxf(v0, v1);
  #pragma unroll
  for (int off = 32; off > 0; off >>= 1) m = fmaxf(m, __shfl_xor(m, off));
  float e0 = __expf(v0 - m);
  float e1 = (lane < 36) ? __expf(v1 - m) : 0.f;
  float s = e0 + e1;
  #pragma unroll
  for (int off = 32; off > 0; off >>= 1) s += __shfl_xor(s, off);
  float inv = 1.f / s;
  e0 *= inv; e1 *= inv;

  if (outT == nullptr) {
    outR[i * KP + lane] = f2bf_bits(e0);
    outR[i * KP + 64 + lane] = (lane < 36) ? f2bf_bits(e1) : (unsigned short)0;
    return;
  }
  srow[w][lane] = e0;
  if (lane < 36) srow[w][64 + lane] = e1;
  __syncthreads();
  int c2 = 64 + lane;
  int c2c = (c2 < NF) ? c2 : NF - 1;
  float a0=0.f, a1=0.f, a2=0.f, a3=0.f;
  float d0=0.f, d1=0.f, d2=0.f, d3=0.f;
  #pragma unroll 4
  for (int k = 0; k < NF; k += 4) {
    float s0 = srow[w][k], s1 = srow[w][k+1], s2 = srow[w][k+2], s3 = srow[w][k+3];
    a0 = fmaf(s0, W[(k  )*NF + lane], a0);
    a1 = fmaf(s1, W[(k+1)*NF + lane], a1);
    a2 = fmaf(s2, W[(k+2)*NF + lane], a2);
    a3 = fmaf(s3, W[(k+3)*NF + lane], a3);
    d0 = fmaf(s0, W[(k  )*NF + c2c], d0);
    d1 = fmaf(s1, W[(k+1)*NF + c2c], d1);
    d2 = fmaf(s2, W[(k+2)*NF + c2c], d2);
    d3 = fmaf(s3, W[(k+3)*NF + c2c], d3);
  }
  outT[i * KP + lane] = f2bf_bits((a0 + a1) + (a2 + a3));
  outT[i * KP + c2]   = (c2 < NF) ? f2bf_bits((d0 + d1) + (d2 + d3)) : (unsigned short)0;
}

// ---------------- Bpack (verbatim round-13/15)
__global__ __launch_bounds__(256) void bpack_kernel(
    const unsigned short* __restrict__ Sr,
    unsigned short* __restrict__ Bpack) {
  __shared__ unsigned short lds[64 * 128];
  int t = threadIdx.x;
  long r0 = (long)blockIdx.x * 64;
  int w0 = blockIdx.x * 2;
  int nv = (int)((N_REG - r0 < 64) ? (N_REG - r0) : 64);
  #pragma unroll
  for (int q = 0; q < 4; ++q) {
    int idx = q * 256 + t;
    int row = idx >> 4, col8 = (idx & 15) * 8;
    us8 v = {0, 0, 0, 0, 0, 0, 0, 0};
    if (row < nv) v = *reinterpret_cast<const us8*>(Sr + (r0 + row) * KP + col8);
    *reinterpret_cast<us8*>(lds + row * 128 + col8) = v;
  }
  __syncthreads();
  for (int idx = t; idx < 896; idx += 256) {
    int win = idx / 448, rem = idx - win * 448;
    int ni = rem >> 6, lane = rem & 63;
    int lr = lane & 15, lg = lane >> 4;
    if (w0 + win < NWIN) {
      us8 v;
      #pragma unroll
      for (int e = 0; e < 8; ++e)
        v[e] = lds[(win * 32 + lg * 8 + e) * 128 + ni * 16 + lr];
      *reinterpret_cast<us8*>(Bpack + (((long)(w0 + win) * 7 + ni) << 9) + (lane << 3)) = v;
    }
  }
}

// ---------------- fused residual SSE (verbatim round-13/15, 64x128 2D grid)
__global__ __launch_bounds__(256, 3) void resid_kernel(
    const float* __restrict__ X,
    const unsigned short* __restrict__ Tm,
    const unsigned short* __restrict__ Sm,
    const float* __restrict__ bcol,
    const float* __restrict__ brow,
    int N, float* __restrict__ buckets) {
  __shared__ char ldsbuf[49152];
  char* ldsT = ldsbuf;
  char* ldsS = ldsbuf + 16384;
  int t = threadIdx.x;
  int wid = t >> 6, lane = t & 63;
  int lr = lane & 15, lg = lane >> 4;
  long r0blk = (long)blockIdx.y * 64;
  long c0blk = (long)blockIdx.x * 128;
  int r0 = (wid >> 1) * 32;
  int c0 = (wid & 1) * 64;

  bf16x8 sT[4], sS[8];
  #pragma unroll
  for (int i2 = 0; i2 < 4; ++i2) {
    int g = i2 * 256 + t, row = g >> 4, gi = g & 15;
    sT[i2] = *reinterpret_cast<const bf16x8*>(Tm + (r0blk + row) * KP + gi * 8);
  }
  #pragma unroll
  for (int i2 = 0; i2 < 8; ++i2) {
    int g = i2 * 256 + t, row = g >> 4, gi = g & 15;
    sS[i2] = *reinterpret_cast<const bf16x8*>(Sm + (c0blk + row) * KP + gi * 8);
  }

  f32x4 xv[2][4];
  #pragma unroll
  for (int ri = 0; ri < 2; ++ri) {
    long row = r0blk + r0 + ri * 16 + lr;
    #pragma unroll
    for (int ci = 0; ci < 4; ++ci) {
      long cb = c0blk + c0 + ci * 16 + lg * 4;
      if (cb < N) xv[ri][ci] = __builtin_nontemporal_load(
                    reinterpret_cast<const f32x4*>(X + row * N + cb));
      else        xv[ri][ci] = f32x4{0.f, 0.f, 0.f, 0.f};
    }
  }

  #pragma unroll
  for (int i2 = 0; i2 < 4; ++i2) {
    int g = i2 * 256 + t, row = g >> 4, gi = g & 15;
    int off = row * 256 + ((gi * 16) ^ ((row & 7) << 4));
    *reinterpret_cast<bf16x8*>(ldsT + off) = sT[i2];
  }
  #pragma unroll
  for (int i2 = 0; i2 < 8; ++i2) {
    int g = i2 * 256 + t, row = g >> 4, gi = g & 15;
    int off = row * 256 + ((gi * 16) ^ ((row & 7) << 4));
    *reinterpret_cast<bf16x8*>(ldsS + off) = sS[i2];
  }
  __syncthreads();

  f32x4 zero = {0.f, 0.f, 0.f, 0.f};
  f32x4 acc[4][2] = {{zero, zero}, {zero, zero}, {zero, zero}, {zero, zero}};
  #pragma unroll
  for (int ks = 0; ks < 4; ++ks) {
    bf16x8 a[4], bfr[2];
    #pragma unroll
    for (int ci = 0; ci < 4; ++ci) {
      int row = c0 + ci * 16 + lr;
      int off = row * 256 + (((ks * 64) + (lg * 16)) ^ ((row & 7) << 4));
      a[ci] = *reinterpret_cast<const bf16x8*>(ldsS + off);
    }
    #pragma unroll
    for (int ri = 0; ri < 2; ++ri) {
      int row = r0 + ri * 16 + lr;
      int off = row * 256 + (((ks * 64) + (lg * 16)) ^ ((row & 7) << 4));
      bfr[ri] = *reinterpret_cast<const bf16x8*>(ldsT + off);
    }
    #pragma unroll
    for (int ci = 0; ci < 4; ++ci)
      #pragma unroll
      for (int ri = 0; ri < 2; ++ri)
        acc[ci][ri] = __builtin_amdgcn_mfma_f32_16x16x32_bf16(a[ci], bfr[ri], acc[ci][ri], 0, 0, 0);
  }

  float brv[2];
  #pragma unroll
  for (int ri = 0; ri < 2; ++ri) brv[ri] = brow[r0blk + r0 + ri * 16 + lr];

  float sse = 0.f;
  #pragma unroll
  for (int ci = 0; ci < 4; ++ci) {
    long cb = c0blk + c0 + ci * 16 + lg * 4;
    if (cb < N) {
      f32x4 bc = *reinterpret_cast<const f32x4*>(bcol + cb);
      #pragma unroll
      for (int ri = 0; ri < 2; ++ri) {
        f32x4 x = xv[ri][ci];
        #pragma unroll
        for (int j = 0; j < 4; ++j) {
          float e = x[j] - acc[ci][ri][j] - bc[j] - brv[ri];
          sse = fmaf(e, e, sse);
        }
      }
    }
  }
  #pragma unroll
  for (int off = 32; off > 0; off >>= 1) sse += __shfl_xor(sse, off);
  __shared__ float wsum[4];
  if (lane == 0) wsum[wid] = sse;
  __syncthreads();
  if (t == 0)
    atomicAdd(&buckets[(blockIdx.y * gridDim.x + blockIdx.x) & 63],
              wsum[0] + wsum[1] + wsum[2] + wsum[3]);
}

// ---------------- ASr (ni-split depth-1; bf16 NT output — verified r17/r18)
__global__ __launch_bounds__(256, 4) void asr_kernel(
    const float* __restrict__ A,
    const unsigned short* __restrict__ Bpack,
    unsigned short* __restrict__ ASrN) {
  __shared__ char lds[2][16384];
  int t = threadIdx.x;
  int w = t >> 6, lane = t & 63;
  int lr = lane & 15, lg = lane >> 4;
  int gBase = blockIdx.x * 64;
  int kb0 = blockIdx.y * 800;
  int wk0 = blockIdx.y * 25;
  int ni0 = 2 * w;
  int ni1 = 2 * w + 1;
  bool has1 = (ni1 < 7);

  f32x4 zero = {0.f, 0.f, 0.f, 0.f};
  f32x4 acc[4][2];
  #pragma unroll
  for (int gt = 0; gt < 4; ++gt) { acc[gt][0] = zero; acc[gt][1] = zero; }
  f32x4 sreg[8];

  #pragma unroll
  for (int p = 0; p < 4; ++p) {
    int flat = p * 2048 + t * 8;
    int row = flat >> 7, kk = flat & 127;
    const float* src = A + (long)(gBase + row) * N_REG + kb0 + kk;
    sreg[2 * p]     = __builtin_nontemporal_load(reinterpret_cast<const f32x4*>(src));
    sreg[2 * p + 1] = __builtin_nontemporal_load(reinterpret_cast<const f32x4*>(src + 4));
  }

  #pragma unroll 1
  for (int it = 0; it < 7; ++it) {
    char* buf = lds[it & 1];
    if (it < 6) {
      #pragma unroll
      for (int p = 0; p < 4; ++p) {
        int flat = p * 2048 + t * 8;
        int row = flat >> 7, kk = flat & 127;
        int off = row * 256 + ((kk * 2) ^ ((row & 7) << 4));
        *reinterpret_cast<bf16x8*>(buf + off) = cvt8n(sreg[2 * p], sreg[2 * p + 1]);
      }
    } else {   // tail chunk: 32 k
      int row = t >> 2, kk = (t & 3) * 8;
      int off = row * 256 + ((kk * 2) ^ ((row & 7) << 4));
      *reinterpret_cast<bf16x8*>(buf + off) = cvt8n(sreg[0], sreg[1]);
    }
    __syncthreads();

    if (it < 5) {
      #pragma unroll
      for (int p = 0; p < 4; ++p) {
        int flat = p * 2048 + t * 8;
        int row = flat >> 7, kk = flat & 127;
        const float* src = A + (long)(gBase + row) * N_REG + kb0 + (it + 1) * 128 + kk;
        sreg[2 * p]     = __builtin_nontemporal_load(reinterpret_cast<const f32x4*>(src));
        sreg[2 * p + 1] = __builtin_nontemporal_load(reinterpret_cast<const f32x4*>(src + 4));
      }
    } else if (it == 5) {
      int row = t >> 2, kk = (t & 3) * 8;
      const float* src = A + (long)(gBase + row) * N_REG + kb0 + 768 + kk;
      sreg[0] = __builtin_nontemporal_load(reinterpret_cast<const f32x4*>(src));
      sreg[1] = __builtin_nontemporal_load(reinterpret_cast<const f32x4*>(src + 4));
    }

    int nk = (it < 6) ? 4 : 1;
    #pragma unroll 4
    for (int ks = 0; ks < nk; ++ks) {
      bf16x8 afr[4];
      #pragma unroll
      for (int gt = 0; gt < 4; ++gt) {
        int row = gt * 16 + lr;
        int off = row * 256 + (((ks * 64) + lg * 16) ^ ((row & 7) << 4));
        afr[gt] = *reinterpret_cast<const bf16x8*>(buf + off);
      }
      long wbase = ((long)(wk0 + it * 4 + ks) * 7) << 9;
      bf16x8 b0 = *reinterpret_cast<const bf16x8*>(
          Bpack + wbase + ((long)ni0 << 9) + (lane << 3));
      #pragma unroll
      for (int gt = 0; gt < 4; ++gt)
        acc[gt][0] = __builtin_amdgcn_mfma_f32_16x16x32_bf16(afr[gt], b0, acc[gt][0], 0, 0, 0);
      if (has1) {
        bf16x8 b1 = *reinterpret_cast<const bf16x8*>(
            Bpack + wbase + ((long)ni1 << 9) + (lane << 3));
        #pragma unroll
        for (int gt = 0; gt < 4; ++gt)
          acc[gt][1] = __builtin_amdgcn_mfma_f32_16x16x32_bf16(afr[gt], b1, acc[gt][1], 0, 0, 0);
      }
    }
  }

  unsigned short* slice = ASrN + (long)blockIdx.y * (N_GENES * NFT);
  #pragma unroll
  for (int gt = 0; gt < 4; ++gt) {
    int gb = gBase + gt * 16 + lg * 4;
    int f0 = ni0 * 16 + lr;
    #pragma unroll
    for (int j = 0; j < 4; ++j)
      __builtin_nontemporal_store(f2bf_bits(acc[gt][0][j]), &slice[(gb + j) * NFT + f0]);
    if (has1) {
      int f1 = ni1 * 16 + lr;
      #pragma unroll
      for (int j = 0; j < 4; ++j)
        __builtin_nontemporal_store(f2bf_bits(acc[gt][1][j]), &slice[(gb + j) * NFT + f1]);
    }
  }
}

// ---------------- loss4 pieces (bf16 slices; 400 blocks — verified r16/17/18)
__global__ void l4red_kernel(const unsigned short* __restrict__ Sgbf,
                             const unsigned short* __restrict__ ASrN,
                             float* __restrict__ accv) {
  const int NV = N_GENES * NFT / 4;
  int t = blockIdx.x * blockDim.x + threadIdx.x;
  float d = 0.f, n1 = 0.f, n2 = 0.f;
  for (int q = t; q < NV; q += gridDim.x * blockDim.x) {
    int g = q / (NFT / 4);
    int f4 = (q - g * (NFT / 4)) * 4;
    float av0 = 0.f, av1 = 0.f, av2 = 0.f, av3 = 0.f;
    #pragma unroll
    for (int s = 0; s < KSPLIT; ++s) {
      us4 v = __builtin_nontemporal_load(
          reinterpret_cast<const us4*>(ASrN + (long)s * (N_GENES * NFT) + g * NFT + f4));
      av0 += bf2f(v[0]); av1 += bf2f(v[1]); av2 += bf2f(v[2]); av3 += bf2f(v[3]);
    }
    us4 sgb = *reinterpret_cast<const us4*>(Sgbf + g * KP + f4);
    float sg0 = bf2f(sgb[0]), sg1 = bf2f(sgb[1]), sg2 = bf2f(sgb[2]), sg3 = bf2f(sgb[3]);
    d = fmaf(sg0, av0, d); d = fmaf(sg1, av1, d); d = fmaf(sg2, av2, d); d = fmaf(sg3, av3, d);
    n1 = fmaf(sg0, sg0, n1); n1 = fmaf(sg1, sg1, n1); n1 = fmaf(sg2, sg2, n1); n1 = fmaf(sg3, sg3, n1);
    n2 = fmaf(av0, av0, n2); n2 = fmaf(av1, av1, n2); n2 = fmaf(av2, av2, n2); n2 = fmaf(av3, av3, n2);
  }
  #pragma unroll
  for (int off = 32; off > 0; off >>= 1) {
    d += __shfl_xor(d, off); n1 += __shfl_xor(n1, off); n2 += __shfl_xor(n2, off);
  }
  __shared__ float r3[3][4];
  int lane = threadIdx.x & 63, w = threadIdx.x >> 6;
  if (lane == 0) { r3[0][w] = d; r3[1][w] = n1; r3[2][w] = n2; }
  __syncthreads();
  if (threadIdx.x == 0) {
    atomicAdd(&accv[5], r3[0][0] + r3[0][1] + r3[0][2] + r3[0][3]);
    atomicAdd(&accv[6], r3[1][0] + r3[1][1] + r3[1][2] + r3[1][3]);
    atomicAdd(&accv[7], r3[2][0] + r3[2][1] + r3[2][2] + r3[2][3]);
  }
}

// ---------------- finalize (verbatim)
__global__ void fin_kernel(const float* __restrict__ accv,
                           const float* __restrict__ bk1,
                           const float* __restrict__ bk2,
                           const float* __restrict__ alpha,
                           float* __restrict__ out) {
  if (threadIdx.x == 0) {
    float s1 = 0.f, s2 = 0.f;
    for (int i = 0; i < 64; ++i) { s1 += bk1[i]; s2 += bk2[i]; }
    float loss1 = s1 / 64000000.0f;
    float loss2 = s2 / 160000000.0f;
    float loss3 = -accv[2] / (sqrtf(accv[3]) * sqrtf(accv[4]));
    float loss4 = -accv[5] / (sqrtf(accv[6]) * sqrtf(accv[7]));
    float l1 = alpha[0] * loss1, l2 = alpha[1] * loss2;
    float l3 = alpha[2] * loss3, l4 = alpha[3] * loss4;
    out[0] = l1 + l2 + l3 + l4;
    out[1] = l1; out[2] = l2; out[3] = l3; out[4] = l4;
  }
}

// ws layout (bytes): bf16 ASrN layout (r16/17/18)
//   0          : accv f32[16] | 64 bk1[64] | 320 bk2[64]
//   1024       : ASrN bf16 [25][8000][112]  (44,800,000)
//   44,801,024 : T1  bf16 [8000][128]
//   46,849,024 : T2  bf16 [8000][128]
//   48,897,024 : Sg  bf16 [8000][128]
//   50,945,024 : Sr  bf16 [20000][128]
//   56,065,024 : Bpack bf16 [625][7][64][8]

extern "C" void kernel_launch(void* const* d_in, const int* in_sizes, int n_in,
                              void* d_out, int out_size, void* d_ws, size_t ws_size,
                              hipStream_t stream) {
  const float* G  = (const float*)d_in[0];
  const float* R  = (const float*)d_in[1];
  const float* A  = (const float*)d_in[2];
  const float* C1 = (const float*)d_in[3];
  const float* C2 = (const float*)d_in[4];
  const float* Cg = (const float*)d_in[5];
  const float* Cr = (const float*)d_in[6];
  const float* Ag = (const float*)d_in[7];
  const float* Ar = (const float*)d_in[8];
  const float* bg = (const float*)d_in[9];
  const float* br = (const float*)d_in[10];
  const float* b1 = (const float*)d_in[11];
  const float* b2 = (const float*)d_in[12];
  const float* alpha = (const float*)d_in[13];

  char* ws = (char*)d_ws;
  float* accv           = (float*)(ws + 0);
  float* buckets1       = (float*)(ws + 64);
  float* buckets2       = (float*)(ws + 320);
  unsigned short* ASrN  = (unsigned short*)(ws + 1024);
  unsigned short* T1    = (unsigned short*)(ws + 44801024);
  unsigned short* T2    = (unsigned short*)(ws + 46849024);
  unsigned short* Sg    = (unsigned short*)(ws + 48897024);
  unsigned short* Sr    = (unsigned short*)(ws + 50945024);
  unsigned short* Bpack = (unsigned short*)(ws + 56065024);

  hipMemsetAsync(d_ws, 0, 576, stream);

  pre_kernel<<<11001, 256, 0, stream>>>(C1, C2, Cg, Cr, Ag, Ar,
                                        T1, T2, Sg, Sr, accv);
  bpack_kernel<<<313, 256, 0, stream>>>(Sr, Bpack);

  resid_kernel<<<dim3(63, 125), 256, 0, stream>>>(G, T1, Sg, bg, b1, N_GENES, buckets1);
  resid_kernel<<<dim3(157, 125), 256, 0, stream>>>(R, T2, Sr, br, b2, N_REG, buckets2);

  asr_kernel<<<dim3(125, KSPLIT), 256, 0, stream>>>(A, Bpack, ASrN);

  l4red_kernel<<<400, 256, 0, stream>>>(Sg, ASrN, accv);
  fin_kernel<<<1, 64, 0, stream>>>(accv, buckets1, buckets2, alpha, (float*)d_out);
}